// Round 1
// 685.018 us; speedup vs baseline: 1.0595x; 1.0595x over previous
//
#include <hip/hip_runtime.h>
#include <hip/hip_bf16.h>

#define N_NODES 10000
#define N_EDGES 320000
#define D 128
#define H 512

typedef __bf16 bf16x8 __attribute__((ext_vector_type(8)));
typedef float f32x4 __attribute__((ext_vector_type(4)));
typedef unsigned short u16x8 __attribute__((ext_vector_type(8)));

__device__ __forceinline__ unsigned short f2bf(float f) {
    union { float f; unsigned u; } v; v.f = f;
    unsigned r = v.u + 0x7fffu + ((v.u >> 16) & 1u);
    return (unsigned short)(r >> 16);
}

// ---------------- precompute: cast x to bf16 ----------------
__global__ void cast_x_kernel(const float* __restrict__ x, unsigned short* __restrict__ xb) {
    int t = blockIdx.x * 256 + threadIdx.x;        // exactly N_NODES*D/4 threads
    float4 v = reinterpret_cast<const float4*>(x)[t];
    ushort4 o;
    o.x = f2bf(v.x); o.y = f2bf(v.y); o.z = f2bf(v.z); o.w = f2bf(v.w);
    reinterpret_cast<ushort4*>(xb)[t] = o;
}

// ---------------- precompute: swizzle weight [K][N] fp32 -> MFMA-B-frag layout bf16 ----
__global__ void swizzle_w_kernel(const float* __restrict__ W, unsigned short* __restrict__ out,
                                 int K, int Nn) {
    int t = blockIdx.x * 256 + threadIdx.x;
    int total = (K >> 5) * (Nn >> 4) * 64;
    if (t >= total) return;
    int lane = t & 63;
    int tile = t >> 6;
    int ntiles = Nn >> 4;
    int nt = tile % ntiles;
    int kt = tile / ntiles;
    int k0 = kt * 32 + (lane >> 4) * 8;
    int n  = nt * 16 + (lane & 15);
    unsigned short tmp[8];
#pragma unroll
    for (int j = 0; j < 8; ++j) tmp[j] = f2bf(W[(size_t)(k0 + j) * Nn + n]);
    ushort4* dst = reinterpret_cast<ushort4*>(out + (size_t)t * 8);
    dst[0] = *reinterpret_cast<ushort4*>(&tmp[0]);
    dst[1] = *reinterpret_cast<ushort4*>(&tmp[4]);
}

// ---------------- CSR build: histogram -> scan -> scatter ----------------
__global__ void hist_kernel(const int* __restrict__ eidx, int* __restrict__ deg) {
    int e = blockIdx.x * 256 + threadIdx.x;
    if (e < N_EDGES) atomicAdd(&deg[eidx[N_EDGES + e]], 1);
}

__global__ __launch_bounds__(1024) void scan_kernel(const int* __restrict__ deg,
                                                    int* __restrict__ rowstart,
                                                    int* __restrict__ cursor) {
    __shared__ int wsums[16];
    const int t = threadIdx.x;              // 1024 threads, 10 nodes each
    const int lane = t & 63, wv = t >> 6;
    const int base = t * 10;
    int loc[10];
    int s = 0;
#pragma unroll
    for (int i = 0; i < 10; ++i) {
        int v = (base + i < N_NODES) ? deg[base + i] : 0;
        loc[i] = s; s += v;
    }
    const int tot = s;
    // inclusive scan within wave (64 lanes)
    int inc = tot;
#pragma unroll
    for (int d = 1; d < 64; d <<= 1) {
        int n = __shfl_up(inc, d, 64);
        if (lane >= d) inc += n;
    }
    if (lane == 63) wsums[wv] = inc;
    __syncthreads();
    if (t == 0) {
        int run = 0;
#pragma unroll
        for (int w = 0; w < 16; ++w) { int v = wsums[w]; wsums[w] = run; run += v; }
    }
    __syncthreads();
    const int off = wsums[wv] + inc - tot;   // exclusive offset of this thread
#pragma unroll
    for (int i = 0; i < 10; ++i) {
        int idx = base + i;
        if (idx < N_NODES) { int v = off + loc[i]; rowstart[idx] = v; cursor[idx] = v; }
    }
    if (t == 1023) rowstart[N_NODES] = off + tot;   // = N_EDGES
}

__global__ void scatter_kernel(const int* __restrict__ eidx, int* __restrict__ cursor,
                               int* __restrict__ elist) {
    int e = blockIdx.x * 256 + threadIdx.x;
    if (e < N_EDGES) {
        int p = atomicAdd(&cursor[eidx[N_EDGES + e]], 1);
        elist[p] = e;
    }
}

// ---------------- fused edge MLP (no scatter: stores only) ----------------
// block = 256 thr (4 waves), tile = 64 edges.
// GEMM1 single pass: acc1[j], j=h*2+nn, ntile = (j>>1)*8 + wave*2 + (j&1); A-tile read ONCE.
__global__ __launch_bounds__(256, 2) void edge_mlp_kernel(
    const unsigned short* __restrict__ xb,
    const int* __restrict__ eidx,
    const float* __restrict__ edge_attr,
    const unsigned short* __restrict__ We1s,
    const float* __restrict__ be1,
    const unsigned short* __restrict__ We2s,
    const float* __restrict__ be2,
    float* __restrict__ out_edges)
{
    __shared__ unsigned short sA[64 * 392];   // [64][384+8] bf16
    __shared__ unsigned short sH[64 * 136];   // [64][128+8] bf16 hidden chunk

    const int tid = threadIdx.x;
    const int wave = tid >> 6, lane = tid & 63;
    const int e0 = blockIdx.x * 64;
    const int l15 = lane & 15;
    const int q8 = (lane >> 4) * 8;

    // ---- stage A: concat(x[s], x[r], edge_attr) as bf16 ----
#pragma unroll
    for (int seg = 0; seg < 2; ++seg) {
        for (int c = tid; c < 1024; c += 256) {
            int row = c >> 4;
            int off = (c & 15) << 3;
            int e = e0 + row;
            int node = eidx[seg * N_EDGES + e];
            *reinterpret_cast<bf16x8*>(&sA[row * 392 + seg * 128 + off]) =
                *reinterpret_cast<const bf16x8*>(&xb[(size_t)node * 128 + off]);
        }
    }
    for (int c = tid; c < 1024; c += 256) {
        int row = c >> 4;
        int off = (c & 15) << 3;
        int e = e0 + row;
        const float4* src = reinterpret_cast<const float4*>(&edge_attr[(size_t)e * 128 + off]);
        float4 v0 = src[0], v1 = src[1];
        u16x8 o;
        o[0] = f2bf(v0.x); o[1] = f2bf(v0.y); o[2] = f2bf(v0.z); o[3] = f2bf(v0.w);
        o[4] = f2bf(v1.x); o[5] = f2bf(v1.y); o[6] = f2bf(v1.z); o[7] = f2bf(v1.w);
        *reinterpret_cast<u16x8*>(&sA[row * 392 + 256 + off]) = o;
    }
    __syncthreads();

    f32x4 acc1[8][4];
#pragma unroll
    for (int j = 0; j < 8; ++j)
#pragma unroll
        for (int mt = 0; mt < 4; ++mt) acc1[j][mt] = (f32x4){0.f, 0.f, 0.f, 0.f};
    f32x4 acc2[2][4];
#pragma unroll
    for (int nn = 0; nn < 2; ++nn)
#pragma unroll
        for (int mt = 0; mt < 4; ++mt) acc2[nn][mt] = (f32x4){0.f, 0.f, 0.f, 0.f};

    // ---- GEMM1: one pass over K=384, wave owns 8 n-tiles (A LDS reads /4) ----
#pragma unroll 2
    for (int kt = 0; kt < 12; ++kt) {
        bf16x8 a[4];
#pragma unroll
        for (int mt = 0; mt < 4; ++mt)
            a[mt] = *reinterpret_cast<const bf16x8*>(&sA[(mt * 16 + l15) * 392 + kt * 32 + q8]);
#pragma unroll
        for (int j = 0; j < 8; ++j) {
            int ntile = (j >> 1) * 8 + wave * 2 + (j & 1);
            bf16x8 b = *reinterpret_cast<const bf16x8*>(
                &We1s[(((size_t)kt * 32 + ntile) * 64 + lane) * 8]);
#pragma unroll
            for (int mt = 0; mt < 4; ++mt)
                acc1[j][mt] = __builtin_amdgcn_mfma_f32_16x16x32_bf16(a[mt], b, acc1[j][mt], 0, 0, 0);
        }
    }

    // ---- hidden chunks -> GEMM2 (h fully unrolled: acc1 statically indexed) ----
#pragma unroll
    for (int h = 0; h < 4; ++h) {
        __syncthreads();   // previous chunk's GEMM2 reads of sH are done
#pragma unroll
        for (int nn = 0; nn < 2; ++nn) {
            int cc = (wave * 2 + nn) * 16 + l15;
            float bias = be1[h * 128 + cc];
#pragma unroll
            for (int mt = 0; mt < 4; ++mt)
#pragma unroll
                for (int r = 0; r < 4; ++r) {
                    float v = acc1[h * 2 + nn][mt][r] + bias;
                    v = v > 0.f ? v : 0.f;
                    int row = mt * 16 + (lane >> 4) * 4 + r;
                    sH[row * 136 + cc] = f2bf(v);
                }
        }
        __syncthreads();

#pragma unroll
        for (int kt = 0; kt < 4; ++kt) {
            bf16x8 a[4];
#pragma unroll
            for (int mt = 0; mt < 4; ++mt)
                a[mt] = *reinterpret_cast<const bf16x8*>(&sH[(mt * 16 + l15) * 136 + kt * 32 + q8]);
#pragma unroll
            for (int nn = 0; nn < 2; ++nn) {
                int ntile = wave * 2 + nn;           // 0..7 over D=128
                bf16x8 b = *reinterpret_cast<const bf16x8*>(
                    &We2s[(((size_t)(h * 4 + kt) * 8 + ntile) * 64 + lane) * 8]);
#pragma unroll
                for (int mt = 0; mt < 4; ++mt)
                    acc2[nn][mt] = __builtin_amdgcn_mfma_f32_16x16x32_bf16(a[mt], b, acc2[nn][mt], 0, 0, 0);
            }
        }
    }

    // ---- epilogue: plain stores only (no atomics) ----
#pragma unroll
    for (int nn = 0; nn < 2; ++nn) {
        int cc = (wave * 2 + nn) * 16 + l15;
        float bias = be2[cc];
#pragma unroll
        for (int mt = 0; mt < 4; ++mt)
#pragma unroll
            for (int r = 0; r < 4; ++r) {
                int row = mt * 16 + (lane >> 4) * 4 + r;
                out_edges[(size_t)(e0 + row) * 128 + cc] = acc2[nn][mt][r] + bias;
            }
    }
}

// ---------------- fused node MLP: CSR aggregation + MLP ----------------
__global__ __launch_bounds__(256, 2) void node_mlp_kernel(
    const unsigned short* __restrict__ xb,
    const float* __restrict__ out_edges,
    const int* __restrict__ rowstart,
    const int* __restrict__ elist,
    const unsigned short* __restrict__ Wn1s,
    const float* __restrict__ bn1,
    const unsigned short* __restrict__ Wn2s,
    const float* __restrict__ bn2,
    float* __restrict__ out_nodes)
{
    __shared__ unsigned short sA[64 * 264];   // [64][256+8] bf16
    __shared__ unsigned short sH[64 * 136];

    const int tid = threadIdx.x;
    const int wave = tid >> 6, lane = tid & 63;
    const int n0 = blockIdx.x * 64;
    const int l15 = lane & 15;
    const int q8 = (lane >> 4) * 8;

    // stage part 1: x (bf16)
    for (int c = tid; c < 1024; c += 256) {
        int row = c >> 4;
        int off = (c & 15) << 3;
        int node = n0 + row;
        bf16x8 v = {};
        if (node < N_NODES)
            v = *reinterpret_cast<const bf16x8*>(&xb[(size_t)node * 128 + off]);
        *reinterpret_cast<bf16x8*>(&sA[row * 264 + off]) = v;
    }

    // stage part 2: aggregate incoming edges via CSR (4 threads per node, 32 cols each)
    {
        int row = tid >> 2, chunk = tid & 3;
        int node = n0 + row;
        f32x4 ag[8];
#pragma unroll
        for (int q = 0; q < 8; ++q) ag[q] = (f32x4){0.f, 0.f, 0.f, 0.f};
        if (node < N_NODES) {
            int r0 = rowstart[node], r1 = rowstart[node + 1];
            for (int j = r0; j < r1; ++j) {
                int e = elist[j];
                const f32x4* src =
                    reinterpret_cast<const f32x4*>(&out_edges[(size_t)e * 128 + chunk * 32]);
#pragma unroll
                for (int q = 0; q < 8; ++q) ag[q] += src[q];
            }
        }
#pragma unroll
        for (int q = 0; q < 4; ++q) {
            u16x8 o;
            o[0] = f2bf(ag[2 * q][0]); o[1] = f2bf(ag[2 * q][1]);
            o[2] = f2bf(ag[2 * q][2]); o[3] = f2bf(ag[2 * q][3]);
            o[4] = f2bf(ag[2 * q + 1][0]); o[5] = f2bf(ag[2 * q + 1][1]);
            o[6] = f2bf(ag[2 * q + 1][2]); o[7] = f2bf(ag[2 * q + 1][3]);
            *reinterpret_cast<u16x8*>(&sA[row * 264 + 128 + chunk * 32 + q * 8]) = o;
        }
    }
    __syncthreads();

    f32x4 acc1[8][4];
#pragma unroll
    for (int j = 0; j < 8; ++j)
#pragma unroll
        for (int mt = 0; mt < 4; ++mt) acc1[j][mt] = (f32x4){0.f, 0.f, 0.f, 0.f};
    f32x4 acc2[2][4];
#pragma unroll
    for (int nn = 0; nn < 2; ++nn)
#pragma unroll
        for (int mt = 0; mt < 4; ++mt) acc2[nn][mt] = (f32x4){0.f, 0.f, 0.f, 0.f};

    // GEMM1 single pass over K=256
#pragma unroll 2
    for (int kt = 0; kt < 8; ++kt) {
        bf16x8 a[4];
#pragma unroll
        for (int mt = 0; mt < 4; ++mt)
            a[mt] = *reinterpret_cast<const bf16x8*>(&sA[(mt * 16 + l15) * 264 + kt * 32 + q8]);
#pragma unroll
        for (int j = 0; j < 8; ++j) {
            int ntile = (j >> 1) * 8 + wave * 2 + (j & 1);
            bf16x8 b = *reinterpret_cast<const bf16x8*>(
                &Wn1s[(((size_t)kt * 32 + ntile) * 64 + lane) * 8]);
#pragma unroll
            for (int mt = 0; mt < 4; ++mt)
                acc1[j][mt] = __builtin_amdgcn_mfma_f32_16x16x32_bf16(a[mt], b, acc1[j][mt], 0, 0, 0);
        }
    }

#pragma unroll
    for (int h = 0; h < 4; ++h) {
        __syncthreads();
#pragma unroll
        for (int nn = 0; nn < 2; ++nn) {
            int cc = (wave * 2 + nn) * 16 + l15;
            float bias = bn1[h * 128 + cc];
#pragma unroll
            for (int mt = 0; mt < 4; ++mt)
#pragma unroll
                for (int r = 0; r < 4; ++r) {
                    float v = acc1[h * 2 + nn][mt][r] + bias;
                    v = v > 0.f ? v : 0.f;
                    int row = mt * 16 + (lane >> 4) * 4 + r;
                    sH[row * 136 + cc] = f2bf(v);
                }
        }
        __syncthreads();

#pragma unroll
        for (int kt = 0; kt < 4; ++kt) {
            bf16x8 a[4];
#pragma unroll
            for (int mt = 0; mt < 4; ++mt)
                a[mt] = *reinterpret_cast<const bf16x8*>(&sH[(mt * 16 + l15) * 136 + kt * 32 + q8]);
#pragma unroll
            for (int nn = 0; nn < 2; ++nn) {
                int ntile = wave * 2 + nn;
                bf16x8 b = *reinterpret_cast<const bf16x8*>(
                    &Wn2s[(((size_t)(h * 4 + kt) * 8 + ntile) * 64 + lane) * 8]);
#pragma unroll
                for (int mt = 0; mt < 4; ++mt)
                    acc2[nn][mt] = __builtin_amdgcn_mfma_f32_16x16x32_bf16(a[mt], b, acc2[nn][mt], 0, 0, 0);
            }
        }
    }

#pragma unroll
    for (int nn = 0; nn < 2; ++nn) {
        int cc = (wave * 2 + nn) * 16 + l15;
        float bias = bn2[cc];
#pragma unroll
        for (int mt = 0; mt < 4; ++mt)
#pragma unroll
            for (int r = 0; r < 4; ++r) {
                int row = mt * 16 + (lane >> 4) * 4 + r;
                int node = n0 + row;
                if (node < N_NODES)
                    out_nodes[(size_t)node * 128 + cc] = acc2[nn][mt][r] + bias;
            }
    }
}

extern "C" void kernel_launch(void* const* d_in, const int* in_sizes, int n_in,
                              void* d_out, int out_size, void* d_ws, size_t ws_size,
                              hipStream_t stream) {
    const float* x         = (const float*)d_in[0];
    const int*   eidx      = (const int*)d_in[1];
    const float* edge_attr = (const float*)d_in[2];
    const float* We1       = (const float*)d_in[3];
    const float* be1       = (const float*)d_in[4];
    const float* We2       = (const float*)d_in[5];
    const float* be2       = (const float*)d_in[6];
    const float* Wn1       = (const float*)d_in[7];
    const float* bn1       = (const float*)d_in[8];
    const float* Wn2       = (const float*)d_in[9];
    const float* bn2       = (const float*)d_in[10];
    float* out = (float*)d_out;

    char* ws = (char*)d_ws;
    size_t off = 0;
    auto alloc = [&](size_t bytes) {
        void* p = ws + off;
        off += (bytes + 255) & ~(size_t)255;
        return p;
    };
    unsigned short* xb   = (unsigned short*)alloc((size_t)N_NODES * D * 2);
    unsigned short* We1s = (unsigned short*)alloc((size_t)384 * 512 * 2);
    unsigned short* We2s = (unsigned short*)alloc((size_t)512 * 128 * 2);
    unsigned short* Wn1s = (unsigned short*)alloc((size_t)256 * 512 * 2);
    unsigned short* Wn2s = (unsigned short*)alloc((size_t)512 * 128 * 2);
    int* deg      = (int*)alloc((size_t)(N_NODES + 1) * 4);
    int* rowstart = (int*)alloc((size_t)(N_NODES + 1) * 4);
    int* cursor   = (int*)alloc((size_t)(N_NODES + 1) * 4);
    int* elist    = (int*)alloc((size_t)N_EDGES * 4);

    float* out_edges = out + (size_t)N_NODES * D;

    hipMemsetAsync(deg, 0, (size_t)N_NODES * sizeof(int), stream);
    cast_x_kernel<<<(N_NODES * D / 4 + 255) / 256, 256, 0, stream>>>(x, xb);
    swizzle_w_kernel<<<(12 * 32 * 64 + 255) / 256, 256, 0, stream>>>(We1, We1s, 384, 512);
    swizzle_w_kernel<<<(16 * 8 * 64 + 255) / 256, 256, 0, stream>>>(We2, We2s, 512, 128);
    swizzle_w_kernel<<<(8 * 32 * 64 + 255) / 256, 256, 0, stream>>>(Wn1, Wn1s, 256, 512);
    swizzle_w_kernel<<<(16 * 8 * 64 + 255) / 256, 256, 0, stream>>>(Wn2, Wn2s, 512, 128);

    // CSR build (int atomics only, ~640k total)
    hist_kernel<<<(N_EDGES + 255) / 256, 256, 0, stream>>>(eidx, deg);
    scan_kernel<<<1, 1024, 0, stream>>>(deg, rowstart, cursor);
    scatter_kernel<<<(N_EDGES + 255) / 256, 256, 0, stream>>>(eidx, cursor, elist);

    edge_mlp_kernel<<<N_EDGES / 64, 256, 0, stream>>>(
        xb, eidx, edge_attr, We1s, be1, We2s, be2, out_edges);
    node_mlp_kernel<<<(N_NODES + 63) / 64, 256, 0, stream>>>(
        xb, out_edges, rowstart, elist, Wn1s, bn1, Wn2s, bn2, out);
}